// Round 1
// baseline (84783.014 us; speedup 1.0000x reference)
//
#include <hip/hip_runtime.h>
#include <hip/hip_bf16.h>

// Problem constants
#define HH 1024
#define BB 128
#define TT 512

typedef float  f32x4 __attribute__((ext_vector_type(4)));
typedef short  s16x8 __attribute__((ext_vector_type(8)));

__device__ __forceinline__ unsigned short bf16b(float f) {
    union { __hip_bfloat16 h; unsigned short u; } cv;
    cv.h = __float2bfloat16(f);
    return cv.u;
}

__device__ __forceinline__ float gelu_exact(float x) {
    return 0.5f * x * (1.0f + erff(x * 0.70710678118654752440f));
}

// ---------------------------------------------------------------------------
// Pack fp32 weight W[K][N] (row-major) into MFMA B-fragment layout, bf16:
//   P[((ntile*KT + ktile)*64 + lane)*8 + j] = bf16(W[ktile*32 + (lane>>4)*8 + j][ntile*16 + (lane&15)])
// Consumer loads 16 B/lane contiguous, fully coalesced.
// ---------------------------------------------------------------------------
__global__ __launch_bounds__(256) void pack_w_kernel(const float* __restrict__ W,
                                                     unsigned short* __restrict__ P,
                                                     int K, int N) {
    int tid = blockIdx.x * 256 + threadIdx.x;
    int KT = K >> 5;
    int total = (N >> 4) * KT * 64;
    if (tid >= total) return;
    int lane  = tid & 63;
    int ktile = (tid >> 6) % KT;
    int ntile = (tid >> 6) / KT;
    int k0 = ktile * 32 + (lane >> 4) * 8;
    int n  = ntile * 16 + (lane & 15);
    unsigned short tmp[8];
#pragma unroll
    for (int j = 0; j < 8; ++j)
        tmp[j] = bf16b(W[(size_t)(k0 + j) * N + n]);
    *reinterpret_cast<s16x8*>(P + (size_t)tid * 8) = *reinterpret_cast<const s16x8*>(tmp);
}

// ---------------------------------------------------------------------------
// Shared GEMM geometry: M=128, N=1024.
// Block = 512 threads = 8 waves arranged 2(M) x 4(N); wave tile 32x32.
// Grid = dim3(8, 2): WG tile 64(M) x 128(N).
// MFMA 16x16x32 bf16. A-frag: lane holds A[row=lane&15][k=(lane>>4)*8+j].
// D-frag: row=(lane>>4)*4+reg, col=lane&15  (m89-verified mapping).
// ---------------------------------------------------------------------------

// Layer-1 MLP kernel: Hout = gelu( [x_t, S] @ Wp + bias ), K = 2048.
// x_t read from fp32 frame_features (row stride T*H), S is bf16 [B][H].
__global__ __launch_bounds__(512) void layer1_kernel(
    const float* __restrict__ X, int t,
    const unsigned short* __restrict__ S,
    const unsigned short* __restrict__ Wp,
    const float* __restrict__ bias,
    unsigned short* __restrict__ Hout)
{
    const int KT = 64;  // 2048/32
    int tid  = threadIdx.x;
    int lane = tid & 63;
    int w  = tid >> 6;
    int wm = w >> 2, wn = w & 3;
    int mbase = blockIdx.y * 64 + wm * 32;
    int nbase = blockIdx.x * 128 + wn * 32;
    int r = lane & 15, q = lane >> 4;

    const float* x0 = X + (size_t)(mbase + r) * (TT * HH) + (size_t)t * HH + q * 8;
    const float* x1 = x0 + (size_t)16 * (TT * HH);
    const unsigned short* s0 = S + (size_t)(mbase + r) * HH + q * 8;
    const unsigned short* s1 = s0 + (size_t)16 * HH;
    const unsigned short* bp = Wp + ((size_t)(nbase >> 4) * KT) * 64 * 8 + (size_t)lane * 8;

    f32x4 acc[2][2] = {};

#pragma unroll 2
    for (int kt = 0; kt < 32; ++kt) {   // current-frame half of concat (fp32 -> bf16 on the fly)
        int k = kt * 32;
        f32x4 lo0 = *reinterpret_cast<const f32x4*>(x0 + k);
        f32x4 hi0 = *reinterpret_cast<const f32x4*>(x0 + k + 4);
        f32x4 lo1 = *reinterpret_cast<const f32x4*>(x1 + k);
        f32x4 hi1 = *reinterpret_cast<const f32x4*>(x1 + k + 4);
        s16x8 a0, a1;
#pragma unroll
        for (int j = 0; j < 4; ++j) {
            a0[j]     = (short)bf16b(lo0[j]);
            a0[j + 4] = (short)bf16b(hi0[j]);
            a1[j]     = (short)bf16b(lo1[j]);
            a1[j + 4] = (short)bf16b(hi1[j]);
        }
        s16x8 b0 = *reinterpret_cast<const s16x8*>(bp + (size_t)kt * 64 * 8);
        s16x8 b1 = *reinterpret_cast<const s16x8*>(bp + ((size_t)KT * 64 + (size_t)kt * 64) * 8);
        acc[0][0] = __builtin_amdgcn_mfma_f32_16x16x32_bf16(a0, b0, acc[0][0], 0, 0, 0);
        acc[0][1] = __builtin_amdgcn_mfma_f32_16x16x32_bf16(a0, b1, acc[0][1], 0, 0, 0);
        acc[1][0] = __builtin_amdgcn_mfma_f32_16x16x32_bf16(a1, b0, acc[1][0], 0, 0, 0);
        acc[1][1] = __builtin_amdgcn_mfma_f32_16x16x32_bf16(a1, b1, acc[1][1], 0, 0, 0);
    }
#pragma unroll 2
    for (int kt = 32; kt < 64; ++kt) {  // state/aligned half of concat (bf16 direct)
        int k = (kt - 32) * 32;
        s16x8 a0 = *reinterpret_cast<const s16x8*>(s0 + k);
        s16x8 a1 = *reinterpret_cast<const s16x8*>(s1 + k);
        s16x8 b0 = *reinterpret_cast<const s16x8*>(bp + (size_t)kt * 64 * 8);
        s16x8 b1 = *reinterpret_cast<const s16x8*>(bp + ((size_t)KT * 64 + (size_t)kt * 64) * 8);
        acc[0][0] = __builtin_amdgcn_mfma_f32_16x16x32_bf16(a0, b0, acc[0][0], 0, 0, 0);
        acc[0][1] = __builtin_amdgcn_mfma_f32_16x16x32_bf16(a0, b1, acc[0][1], 0, 0, 0);
        acc[1][0] = __builtin_amdgcn_mfma_f32_16x16x32_bf16(a1, b0, acc[1][0], 0, 0, 0);
        acc[1][1] = __builtin_amdgcn_mfma_f32_16x16x32_bf16(a1, b1, acc[1][1], 0, 0, 0);
    }

#pragma unroll
    for (int ni = 0; ni < 2; ++ni) {
        int col = nbase + ni * 16 + r;
        float bv = bias[col];
#pragma unroll
        for (int mi = 0; mi < 2; ++mi) {
            int row0 = mbase + mi * 16 + q * 4;
#pragma unroll
            for (int j = 0; j < 4; ++j) {
                float v = acc[mi][ni][j] + bv;
                Hout[(size_t)(row0 + j) * HH + col] = bf16b(gelu_exact(v));
            }
        }
    }
}

// Layer-2 kernel for the alignment MLP: aligned = A @ Wp + bias (K=1024).
// Writes fp32 (for the final blend) and bf16 (as next GEMM's A operand).
__global__ __launch_bounds__(512) void align_kernel(
    const unsigned short* __restrict__ A,
    const unsigned short* __restrict__ Wp,
    const float* __restrict__ bias,
    float* __restrict__ Af32,
    unsigned short* __restrict__ Abf16)
{
    const int KT = 32;  // 1024/32
    int tid  = threadIdx.x;
    int lane = tid & 63;
    int w  = tid >> 6;
    int wm = w >> 2, wn = w & 3;
    int mbase = blockIdx.y * 64 + wm * 32;
    int nbase = blockIdx.x * 128 + wn * 32;
    int r = lane & 15, q = lane >> 4;

    const unsigned short* s0 = A + (size_t)(mbase + r) * HH + q * 8;
    const unsigned short* s1 = s0 + (size_t)16 * HH;
    const unsigned short* bp = Wp + ((size_t)(nbase >> 4) * KT) * 64 * 8 + (size_t)lane * 8;

    f32x4 acc[2][2] = {};

#pragma unroll 4
    for (int kt = 0; kt < 32; ++kt) {
        int k = kt * 32;
        s16x8 a0 = *reinterpret_cast<const s16x8*>(s0 + k);
        s16x8 a1 = *reinterpret_cast<const s16x8*>(s1 + k);
        s16x8 b0 = *reinterpret_cast<const s16x8*>(bp + (size_t)kt * 64 * 8);
        s16x8 b1 = *reinterpret_cast<const s16x8*>(bp + ((size_t)KT * 64 + (size_t)kt * 64) * 8);
        acc[0][0] = __builtin_amdgcn_mfma_f32_16x16x32_bf16(a0, b0, acc[0][0], 0, 0, 0);
        acc[0][1] = __builtin_amdgcn_mfma_f32_16x16x32_bf16(a0, b1, acc[0][1], 0, 0, 0);
        acc[1][0] = __builtin_amdgcn_mfma_f32_16x16x32_bf16(a1, b0, acc[1][0], 0, 0, 0);
        acc[1][1] = __builtin_amdgcn_mfma_f32_16x16x32_bf16(a1, b1, acc[1][1], 0, 0, 0);
    }

#pragma unroll
    for (int ni = 0; ni < 2; ++ni) {
        int col = nbase + ni * 16 + r;
        float bv = bias[col];
#pragma unroll
        for (int mi = 0; mi < 2; ++mi) {
            int row0 = mbase + mi * 16 + q * 4;
#pragma unroll
            for (int j = 0; j < 4; ++j) {
                float v = acc[mi][ni][j] + bv;
                Af32 [(size_t)(row0 + j) * HH + col] = v;
                Abf16[(size_t)(row0 + j) * HH + col] = bf16b(v);
            }
        }
    }
}

// Final kernel: g = sigmoid(A @ Wp + bias); out = g*aligned + (1-g)*x_t.
// Writes fp32 output slice and bf16 next-state.
__global__ __launch_bounds__(512) void final_kernel(
    const unsigned short* __restrict__ A,
    const unsigned short* __restrict__ Wp,
    const float* __restrict__ bias,
    const float* __restrict__ Af32,
    const float* __restrict__ X, int t,
    float* __restrict__ Out,
    unsigned short* __restrict__ Sout)
{
    const int KT = 32;
    int tid  = threadIdx.x;
    int lane = tid & 63;
    int w  = tid >> 6;
    int wm = w >> 2, wn = w & 3;
    int mbase = blockIdx.y * 64 + wm * 32;
    int nbase = blockIdx.x * 128 + wn * 32;
    int r = lane & 15, q = lane >> 4;

    const unsigned short* s0 = A + (size_t)(mbase + r) * HH + q * 8;
    const unsigned short* s1 = s0 + (size_t)16 * HH;
    const unsigned short* bp = Wp + ((size_t)(nbase >> 4) * KT) * 64 * 8 + (size_t)lane * 8;

    f32x4 acc[2][2] = {};

#pragma unroll 4
    for (int kt = 0; kt < 32; ++kt) {
        int k = kt * 32;
        s16x8 a0 = *reinterpret_cast<const s16x8*>(s0 + k);
        s16x8 a1 = *reinterpret_cast<const s16x8*>(s1 + k);
        s16x8 b0 = *reinterpret_cast<const s16x8*>(bp + (size_t)kt * 64 * 8);
        s16x8 b1 = *reinterpret_cast<const s16x8*>(bp + ((size_t)KT * 64 + (size_t)kt * 64) * 8);
        acc[0][0] = __builtin_amdgcn_mfma_f32_16x16x32_bf16(a0, b0, acc[0][0], 0, 0, 0);
        acc[0][1] = __builtin_amdgcn_mfma_f32_16x16x32_bf16(a0, b1, acc[0][1], 0, 0, 0);
        acc[1][0] = __builtin_amdgcn_mfma_f32_16x16x32_bf16(a1, b0, acc[1][0], 0, 0, 0);
        acc[1][1] = __builtin_amdgcn_mfma_f32_16x16x32_bf16(a1, b1, acc[1][1], 0, 0, 0);
    }

#pragma unroll
    for (int ni = 0; ni < 2; ++ni) {
        int col = nbase + ni * 16 + r;
        float bv = bias[col];
#pragma unroll
        for (int mi = 0; mi < 2; ++mi) {
            int row0 = mbase + mi * 16 + q * 4;
#pragma unroll
            for (int j = 0; j < 4; ++j) {
                int row = row0 + j;
                float gl = acc[mi][ni][j] + bv;
                float g  = 1.0f / (1.0f + expf(-gl));
                float al = Af32[(size_t)row * HH + col];
                float xv = X[(size_t)row * (TT * HH) + (size_t)t * HH + col];
                float o  = g * al + (1.0f - g) * xv;
                Out [(size_t)row * (TT * HH) + (size_t)t * HH + col] = o;
                Sout[(size_t)row * HH + col] = bf16b(o);
            }
        }
    }
}

extern "C" void kernel_launch(void* const* d_in, const int* in_sizes, int n_in,
                              void* d_out, int out_size, void* d_ws, size_t ws_size,
                              hipStream_t stream) {
    (void)in_sizes; (void)n_in; (void)out_size; (void)ws_size;
    const float* X   = (const float*)d_in[0];
    const float* aw1 = (const float*)d_in[1];
    const float* ab1 = (const float*)d_in[2];
    const float* aw2 = (const float*)d_in[3];
    const float* ab2 = (const float*)d_in[4];
    const float* gw1 = (const float*)d_in[5];
    const float* gb1 = (const float*)d_in[6];
    const float* gw2 = (const float*)d_in[7];
    const float* gb2 = (const float*)d_in[8];
    float* Out = (float*)d_out;

    char* ws = (char*)d_ws;
    unsigned short* p_a1  = (unsigned short*)(ws);                  // 4 MB  (2048x1024 bf16 packed)
    unsigned short* p_g1  = (unsigned short*)(ws + (4u << 20));     // 4 MB
    unsigned short* p_a2  = (unsigned short*)(ws + (8u << 20));     // 2 MB  (1024x1024)
    unsigned short* p_g2  = (unsigned short*)(ws + (10u << 20));    // 2 MB
    unsigned short* state = (unsigned short*)(ws + (12u << 20));    // B*H bf16
    unsigned short* h1    = state + (size_t)BB * HH;
    unsigned short* albf  = h1    + (size_t)BB * HH;
    unsigned short* h2    = albf  + (size_t)BB * HH;
    float*          alf32 = (float*)(h2 + (size_t)BB * HH);         // B*H fp32
    // total ws use: ~13.5 MB

    // Pack weights to bf16 B-fragment layout (per launch; deterministic).
    pack_w_kernel<<<(64 * 64 * 64 + 255) / 256, 256, 0, stream>>>(aw1, p_a1, 2048, 1024);
    pack_w_kernel<<<(64 * 64 * 64 + 255) / 256, 256, 0, stream>>>(gw1, p_g1, 2048, 1024);
    pack_w_kernel<<<(64 * 32 * 64 + 255) / 256, 256, 0, stream>>>(aw2, p_a2, 1024, 1024);
    pack_w_kernel<<<(64 * 32 * 64 + 255) / 256, 256, 0, stream>>>(gw2, p_g2, 1024, 1024);
    hipMemsetAsync(state, 0, (size_t)BB * HH * sizeof(unsigned short), stream);

    dim3 grid(8, 2), blk(512);
    for (int t = 0; t < TT; ++t) {
        layer1_kernel<<<grid, blk, 0, stream>>>(X, t, state, p_a1, ab1, h1);
        align_kernel <<<grid, blk, 0, stream>>>(h1, p_a2, ab2, alf32, albf);
        layer1_kernel<<<grid, blk, 0, stream>>>(X, t, albf, p_g1, gb1, h2);
        final_kernel <<<grid, blk, 0, stream>>>(h2, p_g2, gb2, alf32, X, t, Out, state);
    }
}

// Round 2
// 53296.283 us; speedup vs baseline: 1.5908x; 1.5908x over previous
//
#include <hip/hip_runtime.h>
#include <hip/hip_bf16.h>

// Problem constants
#define HH 1024
#define BB 128
#define TT 512
#define NWG 128      // persistent workgroups: (MP=4) x (NP=32)
#define MP 4
#define NP 32

typedef float  f32x4 __attribute__((ext_vector_type(4)));
typedef short  s16x8 __attribute__((ext_vector_type(8)));

__device__ __forceinline__ unsigned short bf16b(float f) {
    union { __hip_bfloat16 h; unsigned short u; } cv;
    cv.h = __float2bfloat16(f);
    return cv.u;
}

__device__ __forceinline__ float gelu_exact(float x) {
    return 0.5f * x * (1.0f + erff(x * 0.70710678118654752440f));
}

// ---------------------------------------------------------------------------
// Pack fp32 weight W[K][N] (row-major) into MFMA B-fragment layout, bf16:
//   P[((ntile*KT + ktile)*64 + lane)*8 + j] =
//       bf16(W[ktile*32 + (lane>>4)*8 + j][ntile*16 + (lane&15)])
// ---------------------------------------------------------------------------
__global__ __launch_bounds__(256) void pack_w_kernel(const float* __restrict__ W,
                                                     unsigned short* __restrict__ P,
                                                     int K, int N) {
    int tid = blockIdx.x * 256 + threadIdx.x;
    int KT = K >> 5;
    int total = (N >> 4) * KT * 64;
    if (tid >= total) return;
    int lane  = tid & 63;
    int ktile = (tid >> 6) % KT;
    int ntile = (tid >> 6) / KT;
    int k0 = ktile * 32 + (lane >> 4) * 8;
    int n  = ntile * 16 + (lane & 15);
    unsigned short tmp[8];
#pragma unroll
    for (int j = 0; j < 8; ++j)
        tmp[j] = bf16b(W[(size_t)(k0 + j) * N + n]);
    *reinterpret_cast<s16x8*>(P + (size_t)tid * 8) = *reinterpret_cast<const s16x8*>(tmp);
}

// ---------------------------------------------------------------------------
// Device-wide barrier (all NWG blocks co-resident). Sense via monotonically
// increasing round number. Arrive = ACQ_REL fetch_add (releases my prior
// writes, acquires others'); last arriver resets count then release-stores
// the round flag; spinners acquire-load it (acquire -> L1 invalidate).
// ---------------------------------------------------------------------------
__device__ __forceinline__ void gbar(unsigned* cnt, unsigned* flag, unsigned r) {
    __syncthreads();
    if (threadIdx.x == 0) {
        unsigned prev = __hip_atomic_fetch_add(cnt, 1u, __ATOMIC_ACQ_REL,
                                               __HIP_MEMORY_SCOPE_AGENT);
        if (prev == (unsigned)(NWG - 1)) {
            __hip_atomic_store(cnt, 0u, __ATOMIC_RELAXED, __HIP_MEMORY_SCOPE_AGENT);
            __hip_atomic_store(flag, r, __ATOMIC_RELEASE, __HIP_MEMORY_SCOPE_AGENT);
        } else {
            while (__hip_atomic_load(flag, __ATOMIC_ACQUIRE,
                                     __HIP_MEMORY_SCOPE_AGENT) < r)
                __builtin_amdgcn_s_sleep(2);
        }
    }
    __syncthreads();
}

// ---------------------------------------------------------------------------
// Persistent kernel. Grid partition per GEMM (M=128, N=1024):
//   wg = blockIdx.x; ng = wg & 31 (N-slice of 32 cols); mg = wg >> 5 (M-slice
//   of 32 rows).  ng-major mod-8 keeps all M-copies of a weight slice on one
//   XCD (wg % 8 == ng % 8) -> weights stay L2-resident per XCD.
// 4 waves per WG: wave tile 16x16, waves arranged 2(M) x 2(N).
// MFMA 16x16x32 bf16; A-frag: lane holds A[lane&15][q*8+j]; D-frag:
// row=q*4+reg, col=lane&15.
// ---------------------------------------------------------------------------
__global__ __launch_bounds__(256, 1) void persist_kernel(
    const float* __restrict__ X,
    const unsigned short* __restrict__ p_a1, const float* __restrict__ ab1,
    const unsigned short* __restrict__ p_a2, const float* __restrict__ ab2,
    const unsigned short* __restrict__ p_g1, const float* __restrict__ gb1,
    const unsigned short* __restrict__ p_g2, const float* __restrict__ gb2,
    float* __restrict__ Out,
    unsigned short* state, unsigned short* h1, unsigned short* albf,
    float* alf32, unsigned short* h2,
    unsigned* bar_cnt, unsigned* bar_flag)
{
    const int wg   = blockIdx.x;
    const int ng   = wg & (NP - 1);
    const int mg   = wg >> 5;
    const int tid  = threadIdx.x;
    const int lane = tid & 63;
    const int w    = tid >> 6;        // 0..3
    const int wm   = w >> 1;          // 0..1
    const int wn   = w & 1;           // 0..1
    const int r    = lane & 15;
    const int q    = lane >> 4;

    const int mrow = mg * 32 + wm * 16;          // wave's M base
    const int ncol = ng * 32 + wn * 16;          // wave's N base
    const int ntile = ncol >> 4;                 // B-fragment n-tile index

    // Per-wave A-row bases (row = mrow + r)
    const size_t arow_off = (size_t)(mrow + r) * HH + q * 8;
    const float* xrow = X + (size_t)(mrow + r) * (TT * HH) + q * 8;

    // B-fragment bases: frag(kt) at ((ntile*KT + kt)*64 + lane)*8
    const unsigned short* bpa1 = p_a1 + ((size_t)ntile * 64) * 512 + (size_t)lane * 8;
    const unsigned short* bpg1 = p_g1 + ((size_t)ntile * 64) * 512 + (size_t)lane * 8;
    const unsigned short* bpa2 = p_a2 + ((size_t)ntile * 32) * 512 + (size_t)lane * 8;
    const unsigned short* bpg2 = p_g2 + ((size_t)ntile * 32) * 512 + (size_t)lane * 8;

    const float biasA1 = ab1[ncol + r];
    const float biasA2 = ab2[ncol + r];
    const float biasG1 = gb1[ncol + r];
    const float biasG2 = gb2[ncol + r];

    unsigned round = 0;

    for (int t = 0; t < TT; ++t) {
        const float* xt = xrow + (size_t)t * HH;

        // ---------------- G1: h1 = gelu(concat(x_t, state) @ aw1 + ab1) ----
        {
            f32x4 acc = {};
#pragma unroll 4
            for (int kt = 0; kt < 32; ++kt) {           // x half (fp32 -> bf16)
                f32x4 lo = *reinterpret_cast<const f32x4*>(xt + kt * 32);
                f32x4 hi = *reinterpret_cast<const f32x4*>(xt + kt * 32 + 4);
                s16x8 a;
#pragma unroll
                for (int j = 0; j < 4; ++j) {
                    a[j]     = (short)bf16b(lo[j]);
                    a[j + 4] = (short)bf16b(hi[j]);
                }
                s16x8 b = *reinterpret_cast<const s16x8*>(bpa1 + (size_t)kt * 512);
                acc = __builtin_amdgcn_mfma_f32_16x16x32_bf16(a, b, acc, 0, 0, 0);
            }
#pragma unroll 8
            for (int kt = 32; kt < 64; ++kt) {          // state half (bf16)
                s16x8 a = *reinterpret_cast<const s16x8*>(state + arow_off + (kt - 32) * 32);
                s16x8 b = *reinterpret_cast<const s16x8*>(bpa1 + (size_t)kt * 512);
                acc = __builtin_amdgcn_mfma_f32_16x16x32_bf16(a, b, acc, 0, 0, 0);
            }
#pragma unroll
            for (int j = 0; j < 4; ++j) {
                float v = acc[j] + biasA1;
                h1[(size_t)(mrow + q * 4 + j) * HH + ncol + r] = bf16b(gelu_exact(v));
            }
        }
        gbar(bar_cnt, bar_flag, ++round);

        // ---------------- G2: aligned = h1 @ aw2 + ab2 ----------------------
        {
            f32x4 acc = {};
#pragma unroll 8
            for (int kt = 0; kt < 32; ++kt) {
                s16x8 a = *reinterpret_cast<const s16x8*>(h1 + arow_off + kt * 32);
                s16x8 b = *reinterpret_cast<const s16x8*>(bpa2 + (size_t)kt * 512);
                acc = __builtin_amdgcn_mfma_f32_16x16x32_bf16(a, b, acc, 0, 0, 0);
            }
#pragma unroll
            for (int j = 0; j < 4; ++j) {
                float v = acc[j] + biasA2;
                size_t idx = (size_t)(mrow + q * 4 + j) * HH + ncol + r;
                alf32[idx] = v;
                albf [idx] = bf16b(v);
            }
        }
        gbar(bar_cnt, bar_flag, ++round);

        // ---------------- G3: h2 = gelu(concat(x_t, aligned) @ gw1 + gb1) ---
        {
            f32x4 acc = {};
#pragma unroll 4
            for (int kt = 0; kt < 32; ++kt) {
                f32x4 lo = *reinterpret_cast<const f32x4*>(xt + kt * 32);
                f32x4 hi = *reinterpret_cast<const f32x4*>(xt + kt * 32 + 4);
                s16x8 a;
#pragma unroll
                for (int j = 0; j < 4; ++j) {
                    a[j]     = (short)bf16b(lo[j]);
                    a[j + 4] = (short)bf16b(hi[j]);
                }
                s16x8 b = *reinterpret_cast<const s16x8*>(bpg1 + (size_t)kt * 512);
                acc = __builtin_amdgcn_mfma_f32_16x16x32_bf16(a, b, acc, 0, 0, 0);
            }
#pragma unroll 8
            for (int kt = 32; kt < 64; ++kt) {
                s16x8 a = *reinterpret_cast<const s16x8*>(albf + arow_off + (kt - 32) * 32);
                s16x8 b = *reinterpret_cast<const s16x8*>(bpg1 + (size_t)kt * 512);
                acc = __builtin_amdgcn_mfma_f32_16x16x32_bf16(a, b, acc, 0, 0, 0);
            }
#pragma unroll
            for (int j = 0; j < 4; ++j) {
                float v = acc[j] + biasG1;
                h2[(size_t)(mrow + q * 4 + j) * HH + ncol + r] = bf16b(gelu_exact(v));
            }
        }
        gbar(bar_cnt, bar_flag, ++round);

        // ---------------- G4: gate = sigmoid(h2 @ gw2 + gb2); blend ---------
        {
            f32x4 acc = {};
#pragma unroll 8
            for (int kt = 0; kt < 32; ++kt) {
                s16x8 a = *reinterpret_cast<const s16x8*>(h2 + arow_off + kt * 32);
                s16x8 b = *reinterpret_cast<const s16x8*>(bpg2 + (size_t)kt * 512);
                acc = __builtin_amdgcn_mfma_f32_16x16x32_bf16(a, b, acc, 0, 0, 0);
            }
#pragma unroll
            for (int j = 0; j < 4; ++j) {
                int row = mrow + q * 4 + j;
                int col = ncol + r;
                float gl = acc[j] + biasG2;
                float g  = 1.0f / (1.0f + expf(-gl));
                float al = alf32[(size_t)row * HH + col];
                float xv = X[(size_t)row * (TT * HH) + (size_t)t * HH + col];
                float o  = g * al + (1.0f - g) * xv;
                Out  [(size_t)row * (TT * HH) + (size_t)t * HH + col] = o;
                state[(size_t)row * HH + col] = bf16b(o);
            }
        }
        gbar(bar_cnt, bar_flag, ++round);
    }
}

extern "C" void kernel_launch(void* const* d_in, const int* in_sizes, int n_in,
                              void* d_out, int out_size, void* d_ws, size_t ws_size,
                              hipStream_t stream) {
    (void)in_sizes; (void)n_in; (void)out_size; (void)ws_size;
    const float* X   = (const float*)d_in[0];
    const float* aw1 = (const float*)d_in[1];
    const float* ab1 = (const float*)d_in[2];
    const float* aw2 = (const float*)d_in[3];
    const float* ab2 = (const float*)d_in[4];
    const float* gw1 = (const float*)d_in[5];
    const float* gb1 = (const float*)d_in[6];
    const float* gw2 = (const float*)d_in[7];
    const float* gb2 = (const float*)d_in[8];
    float* Out = (float*)d_out;

    char* ws = (char*)d_ws;
    unsigned short* p_a1 = (unsigned short*)(ws);                 // 4 MB
    unsigned short* p_g1 = (unsigned short*)(ws + (4u  << 20));   // 4 MB
    unsigned short* p_a2 = (unsigned short*)(ws + (8u  << 20));   // 2 MB
    unsigned short* p_g2 = (unsigned short*)(ws + (10u << 20));   // 2 MB
    char* ctrl = ws + (12u << 20);
    unsigned* bar_cnt  = (unsigned*)ctrl;                         // 4 B
    unsigned* bar_flag = (unsigned*)(ctrl + 64);                  // 4 B (own line)
    unsigned short* state = (unsigned short*)(ctrl + 4096);       // 256 KB
    unsigned short* h1    = state + (size_t)BB * HH;              // 256 KB
    unsigned short* albf  = h1    + (size_t)BB * HH;              // 256 KB
    unsigned short* h2    = albf  + (size_t)BB * HH;              // 256 KB
    float*          alf32 = (float*)(h2 + (size_t)BB * HH);       // 512 KB
    // total ws use ~13.6 MB

    pack_w_kernel<<<(64 * 64 * 64 + 255) / 256, 256, 0, stream>>>(aw1, p_a1, 2048, 1024);
    pack_w_kernel<<<(64 * 64 * 64 + 255) / 256, 256, 0, stream>>>(gw1, p_g1, 2048, 1024);
    pack_w_kernel<<<(64 * 32 * 64 + 255) / 256, 256, 0, stream>>>(aw2, p_a2, 1024, 1024);
    pack_w_kernel<<<(64 * 32 * 64 + 255) / 256, 256, 0, stream>>>(gw2, p_g2, 1024, 1024);
    // Zero barrier state + recurrent state every call (graph-replay safe).
    hipMemsetAsync(ctrl, 0, 4096 + (size_t)BB * HH * sizeof(unsigned short), stream);

    persist_kernel<<<NWG, 256, 0, stream>>>(X, p_a1, ab1, p_a2, ab2,
                                            p_g1, gb1, p_g2, gb2,
                                            Out, state, h1, albf, alf32, h2,
                                            bar_cnt, bar_flag);
}

// Round 4
// 29276.074 us; speedup vs baseline: 2.8960x; 1.8205x over previous
//
#include <hip/hip_runtime.h>
#include <hip/hip_bf16.h>

// Problem constants
#define HH 1024
#define BB 128
#define TT 512
#define NWG 128      // persistent workgroups: (MP=4) x (NP=32)
#define NTH 512      // 8 waves: 4 output tiles (2M x 2N) x 2 K-halves
#define NP 32

typedef float        f32x4 __attribute__((ext_vector_type(4)));
typedef short        s16x8 __attribute__((ext_vector_type(8)));
typedef unsigned int u32x2 __attribute__((ext_vector_type(2)));

__device__ __forceinline__ unsigned short bf16b(float f) {
    union { __hip_bfloat16 h; unsigned short u; } cv;
    cv.h = __float2bfloat16(f);
    return cv.u;
}

__device__ __forceinline__ float gelu_exact(float x) {
    return 0.5f * x * (1.0f + erff(x * 0.70710678118654752440f));
}

// --- device-coherent (L1+L2-bypass) accesses: data written/read across WGs
// within ONE kernel. No cache invalidation needed -> weights stay cached.
__device__ __forceinline__ void sc_load_b16x8(s16x8& v, const unsigned short* p) {
    asm volatile("global_load_dwordx4 %0, %1, off sc0 sc1" : "=v"(v) : "v"(p));
}
__device__ __forceinline__ void sc_load_f32(float& v, const float* p) {
    asm volatile("global_load_dword %0, %1, off sc0 sc1" : "=v"(v) : "v"(p));
}
__device__ __forceinline__ void sc_load_u32x2(u32x2& v, const unsigned* p) {
    asm volatile("global_load_dwordx2 %0, %1, off sc0 sc1" : "=v"(v) : "v"(p));
}
__device__ __forceinline__ void sc_store_b16(unsigned short* p, unsigned int v) {
    asm volatile("global_store_short %0, %1, off sc0 sc1" :: "v"(p), "v"(v) : "memory");
}
__device__ __forceinline__ void sc_store_f32(float* p, float v) {
    asm volatile("global_store_dword %0, %1, off sc0 sc1" :: "v"(p), "v"(v) : "memory");
}
__device__ __forceinline__ void sc_store_u32(unsigned* p, unsigned int v) {
    asm volatile("global_store_dword %0, %1, off sc0 sc1" :: "v"(p), "v"(v) : "memory");
}
__device__ __forceinline__ void vm_wait0() {
    asm volatile("s_waitcnt vmcnt(0)" ::: "memory");
    __builtin_amdgcn_sched_barrier(0);   // rule #18: block MFMA hoist above wait
}

// ---------------------------------------------------------------------------
// Pack fp32 weight W[K][N] (row-major) into MFMA B-fragment layout, bf16:
//   P[((ntile*KT + ktile)*64 + lane)*8 + j] =
//       bf16(W[ktile*32 + (lane>>4)*8 + j][ntile*16 + (lane&15)])
// ---------------------------------------------------------------------------
__global__ __launch_bounds__(256) void pack_w_kernel(const float* __restrict__ W,
                                                     unsigned short* __restrict__ P,
                                                     int K, int N) {
    int tid = blockIdx.x * 256 + threadIdx.x;
    int KT = K >> 5;
    int total = (N >> 4) * KT * 64;
    if (tid >= total) return;
    int lane  = tid & 63;
    int ktile = (tid >> 6) % KT;
    int ntile = (tid >> 6) / KT;
    int k0 = ktile * 32 + (lane >> 4) * 8;
    int n  = ntile * 16 + (lane & 15);
    unsigned short tmp[8];
#pragma unroll
    for (int j = 0; j < 8; ++j)
        tmp[j] = bf16b(W[(size_t)(k0 + j) * N + n]);
    *reinterpret_cast<s16x8*>(P + (size_t)tid * 8) = *reinterpret_cast<const s16x8*>(tmp);
}

// ---------------------------------------------------------------------------
// Flag-array device barrier: NO atomics, NO acquire/release (so no L2
// invalidation). Arrival = sc0sc1 store of round number to own slot after
// vmcnt(0); every WG's wave 0 polls all NWG slots (2 per lane).
// ---------------------------------------------------------------------------
__device__ __forceinline__ void gbar(unsigned* slots, unsigned rnd) {
    asm volatile("s_waitcnt vmcnt(0)" ::: "memory");  // drain my sc-stores
    __syncthreads();                                   // all 8 waves drained
    if (threadIdx.x == 0)
        sc_store_u32(slots + blockIdx.x, rnd);
    if (threadIdx.x < 64) {
        const unsigned* p = slots + (threadIdx.x << 1);
        bool done;
        do {
            u32x2 v;
            sc_load_u32x2(v, p);
            asm volatile("s_waitcnt vmcnt(0)" ::: "memory");
            done = __all(v.x >= rnd && v.y >= rnd);
        } while (!done);
    }
    __syncthreads();
}

// K-loop over a bf16 activation buffer read with device-coherent loads.
// Abase includes the wave's row offset (+ q*8); A k-offsets are blk-local
// (0..nblk*8-1)*32.  bp points at the FIRST B-fragment for this segment
// (pre-offset by the caller for K-split segments).
__device__ __forceinline__ f32x4 kloop_sc(const unsigned short* Abase,
                                          const unsigned short* bp,
                                          int nblk) {
    f32x4 acc = {};
    for (int blk = 0; blk < nblk; ++blk) {
        int kb = blk * 8;
        s16x8 a[8], b[8];
#pragma unroll
        for (int j = 0; j < 8; ++j)
            sc_load_b16x8(a[j], Abase + (size_t)(kb + j) * 32);
#pragma unroll
        for (int j = 0; j < 8; ++j)
            b[j] = *reinterpret_cast<const s16x8*>(bp + (size_t)(kb + j) * 512);
        vm_wait0();
#pragma unroll
        for (int j = 0; j < 8; ++j)
            acc = __builtin_amdgcn_mfma_f32_16x16x32_bf16(a[j], b[j], acc, 0, 0, 0);
    }
    return acc;
}

// K-loop over the fp32 input frame (read-only -> plain cached loads).
__device__ __forceinline__ f32x4 kloop_x(const float* xt, const unsigned short* bp) {
    f32x4 acc = {};
#pragma unroll 4
    for (int kt = 0; kt < 32; ++kt) {
        f32x4 lo = *reinterpret_cast<const f32x4*>(xt + kt * 32);
        f32x4 hi = *reinterpret_cast<const f32x4*>(xt + kt * 32 + 4);
        s16x8 a;
#pragma unroll
        for (int j = 0; j < 4; ++j) {
            a[j]     = (short)bf16b(lo[j]);
            a[j + 4] = (short)bf16b(hi[j]);
        }
        s16x8 b = *reinterpret_cast<const s16x8*>(bp + (size_t)kt * 512);
        acc = __builtin_amdgcn_mfma_f32_16x16x32_bf16(a, b, acc, 0, 0, 0);
    }
    return acc;
}

// ---------------------------------------------------------------------------
// Persistent kernel. Partition per GEMM (M=128, N=1024):
//   ng = wg & 31 -> 32-col slice; mg = wg >> 5 -> 32-row slice.
//   (wg % 8 == ng % 8 keeps all M-copies of a weight slice on one XCD.)
// 8 waves: tile = w&3 (2M x 2N of 16x16), khalf = w>>2 splits K.
// khalf-1 partials reduced into khalf-0 via 4 KB LDS.
// Weights/X/biases: plain cached loads. Activations: sc0sc1 coherent.
// ---------------------------------------------------------------------------
__global__ __launch_bounds__(512, 2) void persist_kernel(
    const float* __restrict__ X,
    const unsigned short* __restrict__ p_a1, const float* __restrict__ ab1,
    const unsigned short* __restrict__ p_a2, const float* __restrict__ ab2,
    const unsigned short* __restrict__ p_g1, const float* __restrict__ gb1,
    const unsigned short* __restrict__ p_g2, const float* __restrict__ gb2,
    float* __restrict__ Out,
    unsigned short* state, unsigned short* h1, unsigned short* albf,
    float* alf32, unsigned short* h2,
    unsigned* slots)
{
    __shared__ f32x4 red[4][64];

    const int wg    = blockIdx.x;
    const int ng    = wg & (NP - 1);
    const int mg    = wg >> 5;
    const int tid   = threadIdx.x;
    const int lane  = tid & 63;
    const int w     = tid >> 6;       // 0..7
    const int tile  = w & 3;          // 2M x 2N
    const int khalf = w >> 2;         // 0..1
    const int wm    = tile >> 1;
    const int wn    = tile & 1;
    const int r     = lane & 15;
    const int q     = lane >> 4;

    const int mrow  = mg * 32 + wm * 16;
    const int ncol  = ng * 32 + wn * 16;
    const int ntile = ncol >> 4;

    const size_t arow_off = (size_t)(mrow + r) * HH + q * 8;
    const float* xrow = X + (size_t)(mrow + r) * (TT * HH) + q * 8;

    const unsigned short* bpa1 = p_a1 + ((size_t)ntile * 64) * 512 + (size_t)lane * 8;
    const unsigned short* bpg1 = p_g1 + ((size_t)ntile * 64) * 512 + (size_t)lane * 8;
    const unsigned short* bpa2 = p_a2 + ((size_t)ntile * 32) * 512 + (size_t)lane * 8;
    const unsigned short* bpg2 = p_g2 + ((size_t)ntile * 32) * 512 + (size_t)lane * 8;

    const float biasA1 = ab1[ncol + r];
    const float biasA2 = ab2[ncol + r];
    const float biasG1 = gb1[ncol + r];
    const float biasG2 = gb2[ncol + r];

    unsigned rnd = 0;

    for (int t = 0; t < TT; ++t) {
        const float* xt = xrow + (size_t)t * HH;

        // ------- G1: h1 = gelu(concat(x_t, state) @ aw1 + ab1), K=2048 -----
        {
            f32x4 acc;
            if (khalf == 0) acc = kloop_x(xt, bpa1);   // K 0..1023 (x, cached)
            else            acc = kloop_sc(state + arow_off,          // K 1024..2047
                                           bpa1 + (size_t)32 * 512, 4);
            if (khalf == 1) red[tile][lane] = acc;
            __syncthreads();
            if (khalf == 0) {
                acc += red[tile][lane];
#pragma unroll
                for (int j = 0; j < 4; ++j) {
                    float v = acc[j] + biasA1;
                    sc_store_b16(h1 + (size_t)(mrow + q * 4 + j) * HH + ncol + r,
                                 bf16b(gelu_exact(v)));
                }
            }
        }
        gbar(slots, ++rnd);

        // ------- G2: aligned = h1 @ aw2 + ab2, K=1024 ----------------------
        {
            f32x4 acc = kloop_sc(h1 + arow_off + (size_t)khalf * 512,
                                 bpa2 + (size_t)khalf * 16 * 512, 2);
            if (khalf == 1) red[tile][lane] = acc;
            __syncthreads();
            if (khalf == 0) {
                acc += red[tile][lane];
#pragma unroll
                for (int j = 0; j < 4; ++j) {
                    float v = acc[j] + biasA2;
                    size_t idx = (size_t)(mrow + q * 4 + j) * HH + ncol + r;
                    sc_store_f32(alf32 + idx, v);
                    sc_store_b16(albf + idx, bf16b(v));
                }
            }
        }
        gbar(slots, ++rnd);

        // ------- G3: h2 = gelu(concat(x_t, aligned) @ gw1 + gb1), K=2048 ---
        {
            f32x4 acc;
            if (khalf == 0) acc = kloop_x(xt, bpg1);
            else            acc = kloop_sc(albf + arow_off,
                                           bpg1 + (size_t)32 * 512, 4);
            if (khalf == 1) red[tile][lane] = acc;
            __syncthreads();
            if (khalf == 0) {
                acc += red[tile][lane];
#pragma unroll
                for (int j = 0; j < 4; ++j) {
                    float v = acc[j] + biasG1;
                    sc_store_b16(h2 + (size_t)(mrow + q * 4 + j) * HH + ncol + r,
                                 bf16b(gelu_exact(v)));
                }
            }
        }
        gbar(slots, ++rnd);

        // ------- G4: gate = sigmoid(h2 @ gw2 + gb2); blend; next state -----
        {
            f32x4 acc = kloop_sc(h2 + arow_off + (size_t)khalf * 512,
                                 bpg2 + (size_t)khalf * 16 * 512, 2);
            if (khalf == 1) red[tile][lane] = acc;
            __syncthreads();
            if (khalf == 0) {
                float al[4];
#pragma unroll
                for (int j = 0; j < 4; ++j)
                    sc_load_f32(al[j], alf32 + (size_t)(mrow + q * 4 + j) * HH + ncol + r);
                acc += red[tile][lane];
                vm_wait0();
#pragma unroll
                for (int j = 0; j < 4; ++j) {
                    int row = mrow + q * 4 + j;
                    int col = ncol + r;
                    float gl = acc[j] + biasG2;
                    float g  = 1.0f / (1.0f + expf(-gl));
                    float xv = X[(size_t)row * (TT * HH) + (size_t)t * HH + col];
                    float o  = g * al[j] + (1.0f - g) * xv;
                    Out[(size_t)row * (TT * HH) + (size_t)t * HH + col] = o;   // plain
                    sc_store_b16(state + (size_t)row * HH + col, bf16b(o));
                }
            }
        }
        gbar(slots, ++rnd);
    }
}

extern "C" void kernel_launch(void* const* d_in, const int* in_sizes, int n_in,
                              void* d_out, int out_size, void* d_ws, size_t ws_size,
                              hipStream_t stream) {
    (void)in_sizes; (void)n_in; (void)out_size; (void)ws_size;
    const float* X   = (const float*)d_in[0];
    const float* aw1 = (const float*)d_in[1];
    const float* ab1 = (const float*)d_in[2];
    const float* aw2 = (const float*)d_in[3];
    const float* ab2 = (const float*)d_in[4];
    const float* gw1 = (const float*)d_in[5];
    const float* gb1 = (const float*)d_in[6];
    const float* gw2 = (const float*)d_in[7];
    const float* gb2 = (const float*)d_in[8];
    float* Out = (float*)d_out;

    char* ws = (char*)d_ws;
    unsigned short* p_a1 = (unsigned short*)(ws);                 // 4 MB
    unsigned short* p_g1 = (unsigned short*)(ws + (4u  << 20));   // 4 MB
    unsigned short* p_a2 = (unsigned short*)(ws + (8u  << 20));   // 2 MB
    unsigned short* p_g2 = (unsigned short*)(ws + (10u << 20));   // 2 MB
    char* ctrl = ws + (12u << 20);
    unsigned* slots = (unsigned*)ctrl;                            // NWG u32 (512 B)
    unsigned short* state = (unsigned short*)(ctrl + 4096);       // 256 KB
    unsigned short* h1    = state + (size_t)BB * HH;              // 256 KB
    unsigned short* albf  = h1    + (size_t)BB * HH;              // 256 KB
    unsigned short* h2    = albf  + (size_t)BB * HH;              // 256 KB
    float*          alf32 = (float*)(h2 + (size_t)BB * HH);       // 512 KB

    pack_w_kernel<<<(64 * 64 * 64 + 255) / 256, 256, 0, stream>>>(aw1, p_a1, 2048, 1024);
    pack_w_kernel<<<(64 * 64 * 64 + 255) / 256, 256, 0, stream>>>(gw1, p_g1, 2048, 1024);
    pack_w_kernel<<<(64 * 32 * 64 + 255) / 256, 256, 0, stream>>>(aw2, p_a2, 1024, 1024);
    pack_w_kernel<<<(64 * 32 * 64 + 255) / 256, 256, 0, stream>>>(gw2, p_g2, 1024, 1024);
    // Zero barrier slots + recurrent state every call (graph-replay safe).
    hipMemsetAsync(ctrl, 0, 4096 + (size_t)BB * HH * sizeof(unsigned short), stream);

    persist_kernel<<<NWG, NTH, 0, stream>>>(X, p_a1, ab1, p_a2, ab2,
                                            p_g1, gb1, p_g2, gb2,
                                            Out, state, h1, albf, alf32, h2,
                                            slots);
}